// Round 2
// baseline (317.566 us; speedup 1.0000x reference)
//
#include <hip/hip_runtime.h>
#include <hip/hip_bf16.h>
#include <stdint.h>

// ---------------- problem constants ----------------
#define DIMC  512
#define NHEAD 16
#define HDIM  32
#define NTOK  65536          // 4*128*128 tokens
#define QKVN  1536           // 3*DIMC
static constexpr float SCALE_F = 0.17677669529663687f;  // HD^-0.5

typedef __attribute__((ext_vector_type(4))) float  f32x4;
typedef __attribute__((ext_vector_type(8))) __bf16 bf16x8;

__device__ __forceinline__ uint16_t f2bf(float f) {
  union { float f; uint32_t u; } v; v.f = f;
  return (uint16_t)((v.u + 0x7FFFu + ((v.u >> 16) & 1u)) >> 16);
}

// async global->LDS, 16B per lane; lds dest must be wave-uniform base (HW adds lane*16)
__device__ __forceinline__ void gload_lds16(const void* g, void* l) {
  __builtin_amdgcn_global_load_lds((const __attribute__((address_space(1))) void*)g,
                                   (__attribute__((address_space(3))) void*)l,
                                   16, 0, 0);
}

// ---------------------------------------------------------------------------
// fp32 -> bf16 convert (vectorized, grid-stride). n4 = element count / 4.
// ---------------------------------------------------------------------------
__global__ void cvt_f32_bf16(const float* __restrict__ src,
                             uint16_t* __restrict__ dst, int n4)
{
  int i = blockIdx.x * blockDim.x + threadIdx.x;
  const int stride = gridDim.x * blockDim.x;
  for (; i < n4; i += stride) {
    const float4 v = ((const float4*)src)[i];
    ushort4 o;
    o.x = f2bf(v.x); o.y = f2bf(v.y); o.z = f2bf(v.z); o.w = f2bf(v.w);
    ((ushort4*)dst)[i] = o;
  }
}

// ---------------------------------------------------------------------------
// GEMM: C[M,N] = A[M,K] @ B[N,K]^T + bias[N]   (bf16 in, fp32 accum)
// m97 structure: 128x128 tile, BK=64, 4 waves (2x2), 4x4 16x16x32 frags/wave.
// OUT_F32: write fp32 C, else bf16 C.
// ---------------------------------------------------------------------------
template <bool OUT_F32>
__global__ __launch_bounds__(256, 2)
void gemm_bias_bf16(const uint16_t* __restrict__ A,
                    const uint16_t* __restrict__ B,
                    const float* __restrict__ bias,
                    void* __restrict__ Cv,
                    int M, int N, int K)
{
  __shared__ __align__(16) __bf16 As[128][64];
  __shared__ __align__(16) __bf16 Bs[128][64];

  const int tid = threadIdx.x;
  const int l  = tid & 63, w = tid >> 6;
  const int wm = w >> 1,  wn = w & 1;
  const int lm = l & 15,  lq = l >> 4;
  const long m0 = (long)blockIdx.y * 128;
  const long n0 = (long)blockIdx.x * 128;

  // staging map: thread tid loads 16B = 8 bf16: row tid>>3 (+32/chunk), col (tid&7)*8
  const int srow = tid >> 3;
  const int scol = (tid & 7) * 8;
  const uint16_t* Ag = A + (m0 + srow) * (long)K + scol;
  const uint16_t* Bg = B + (n0 + srow) * (long)K + scol;
  char* AsW = (char*)(&As[0][0]) + w * 1024;   // wave-uniform LDS base
  char* BsW = (char*)(&Bs[0][0]) + w * 1024;

  f32x4 acc[4][4] = {};

  for (int kt = 0; kt < K; kt += 64) {
#pragma unroll
    for (int c = 0; c < 4; ++c)
      gload_lds16(Ag + (size_t)c * 32 * K + kt, AsW + c * 4096);
#pragma unroll
    for (int c = 0; c < 4; ++c)
      gload_lds16(Bg + (size_t)c * 32 * K + kt, BsW + c * 4096);
    __syncthreads();   // compiler drains vmcnt before s_barrier

#pragma unroll
    for (int kk = 0; kk < 2; ++kk) {
      bf16x8 a[4], b[4];
#pragma unroll
      for (int i = 0; i < 4; ++i)
        a[i] = *(const bf16x8*)(&As[wm * 64 + i * 16 + lm][kk * 32 + lq * 8]);
#pragma unroll
      for (int i = 0; i < 4; ++i)
        b[i] = *(const bf16x8*)(&Bs[wn * 64 + i * 16 + lm][kk * 32 + lq * 8]);
#pragma unroll
      for (int mi = 0; mi < 4; ++mi)
#pragma unroll
        for (int ni = 0; ni < 4; ++ni)
          acc[mi][ni] = __builtin_amdgcn_mfma_f32_16x16x32_bf16(
              a[mi], b[ni], acc[mi][ni], 0, 0, 0);
    }
    __syncthreads();   // all reads done before next stage overwrites
  }

  // epilogue: C/D layout col = l&15, row = (l>>4)*4 + r   [m89/m91]
  float bvals[4];
#pragma unroll
  for (int ni = 0; ni < 4; ++ni)
    bvals[ni] = bias[n0 + wn * 64 + ni * 16 + lm];

#pragma unroll
  for (int mi = 0; mi < 4; ++mi)
#pragma unroll
    for (int ni = 0; ni < 4; ++ni) {
      long m = m0 + wm * 64 + mi * 16 + lq * 4;
      long n = n0 + wn * 64 + ni * 16 + lm;
#pragma unroll
      for (int r = 0; r < 4; ++r) {
        const float val = acc[mi][ni][r] + bvals[ni];
        if (OUT_F32) ((float*)Cv)[(m + r) * (long)N + n] = val;
        else         ((uint16_t*)Cv)[(m + r) * (long)N + n] = f2bf(val);
      }
    }
}

// ---------------------------------------------------------------------------
// Windowed dilated attention: one wave per (group g, head h).
// Group g: d1=g&1, d0=(g>>1)&1, wx=(g>>2)&7, wy=(g>>5)&7, b=g>>8.
// Token n (0..63): iy=n>>3, ix=n&7 ; t = tbase + iy*256 + ix*2.
// RoPE: dims[0..15] rotated by iy*inv[j], dims[16..31] by ix*inv[j],
//       inv[j] = 10000^(-j/8); interleaved pairs (2j, 2j+1).
// ---------------------------------------------------------------------------
__global__ void attn_win(const uint16_t* __restrict__ QKV,  // [NTOK][1536] bf16
                         uint16_t* __restrict__ O)          // [NTOK][512]  bf16
{
  __shared__ __align__(16) __bf16 Pl[4][64][72];   // per-wave P scratch (pad 72)

  const int tid = threadIdx.x;
  const int l  = tid & 63, w = tid >> 6;
  const int lm = l & 15,  lq = l >> 4;
  const int bid = blockIdx.x;
  const int g = bid >> 2;
  const int h = (bid & 3) * 4 + w;

  const int d1 = g & 1, d0 = (g >> 1) & 1;
  const int wx = (g >> 2) & 7, wy = (g >> 5) & 7, bb = g >> 8;
  const long tbase = ((long)(bb * 128 + wy * 16 + d0) * 128) + wx * 16 + d1;

  // per-lane rope inverse-freqs: lane covers dims lq*8..lq*8+7 -> pairs j=(lq&1)*4+i
  f32x4 invs;
#pragma unroll
  for (int i = 0; i < 4; ++i)
    invs[i] = exp2f(-1.6609640474436813f * (float)((lq & 1) * 4 + i)); // -log2(10000)/8

  const int co_q = h * HDIM;
  const int co_k = DIMC + h * HDIM;
  const int co_v = 2 * DIMC + h * HDIM;

  // ---- load Q/K fragments with fused RoPE ----
  bf16x8 qf[4], kf[4];
#pragma unroll
  for (int f = 0; f < 4; ++f) {
    const int n  = f * 16 + lm;          // token index within group
    const int iy = n >> 3, ix = n & 7;
    const float pos = (lq < 2) ? (float)iy : (float)ix;
    const long t = tbase + iy * 256 + ix * 2;
    const uint16_t* qp = QKV + t * QKVN + co_q + lq * 8;
    const uint16_t* kp = QKV + t * QKVN + co_k + lq * 8;
    {
      bf16x8 raw = *(const bf16x8*)qp, o;
#pragma unroll
      for (int i = 0; i < 4; ++i) {
        float x1 = (float)raw[2 * i], x2 = (float)raw[2 * i + 1];
        float s, c; __sincosf(pos * invs[i], &s, &c);
        o[2 * i]     = (__bf16)((x1 * c - x2 * s) * SCALE_F);
        o[2 * i + 1] = (__bf16)((x1 * s + x2 * c) * SCALE_F);
      }
      qf[f] = o;
    }
    {
      bf16x8 raw = *(const bf16x8*)kp, o;
#pragma unroll
      for (int i = 0; i < 4; ++i) {
        float x1 = (float)raw[2 * i], x2 = (float)raw[2 * i + 1];
        float s, c; __sincosf(pos * invs[i], &s, &c);
        o[2 * i]     = (__bf16)(x1 * c - x2 * s);
        o[2 * i + 1] = (__bf16)(x1 * s + x2 * c);
      }
      kf[f] = o;
    }
  }

  // ---- S = Q K^T (scale folded into Q) : 16 MFMAs ----
  const f32x4 fzero = {0.f, 0.f, 0.f, 0.f};
  f32x4 s[4][4];
#pragma unroll
  for (int mi = 0; mi < 4; ++mi)
#pragma unroll
    for (int ni = 0; ni < 4; ++ni)
      s[mi][ni] = __builtin_amdgcn_mfma_f32_16x16x32_bf16(qf[mi], kf[ni], fzero, 0, 0, 0);

  // ---- row softmax (rows live on 16-lane slices; xor-reduce over lm bits) ----
  float rsum[4][4];
#pragma unroll
  for (int mi = 0; mi < 4; ++mi)
#pragma unroll
    for (int r = 0; r < 4; ++r) {
      float m = s[mi][0][r];
#pragma unroll
      for (int ni = 1; ni < 4; ++ni) m = fmaxf(m, s[mi][ni][r]);
      m = fmaxf(m, __shfl_xor(m, 1));
      m = fmaxf(m, __shfl_xor(m, 2));
      m = fmaxf(m, __shfl_xor(m, 4));
      m = fmaxf(m, __shfl_xor(m, 8));
      float sum = 0.f;
#pragma unroll
      for (int ni = 0; ni < 4; ++ni) {
        float p = expf(s[mi][ni][r] - m);
        s[mi][ni][r] = p;                 // keep unnormalized P
        sum += p;
      }
      sum += __shfl_xor(sum, 1);
      sum += __shfl_xor(sum, 2);
      sum += __shfl_xor(sum, 4);
      sum += __shfl_xor(sum, 8);
      rsum[mi][r] = sum;
    }

  // ---- P -> LDS (C-layout) then re-read as A-frags (wave-private, no barrier) ----
#pragma unroll
  for (int mi = 0; mi < 4; ++mi)
#pragma unroll
    for (int ni = 0; ni < 4; ++ni)
#pragma unroll
      for (int r = 0; r < 4; ++r)
        Pl[w][mi * 16 + lq * 4 + r][ni * 16 + lm] = (__bf16)s[mi][ni][r];

  bf16x8 pa[4][2];
#pragma unroll
  for (int mi = 0; mi < 4; ++mi)
#pragma unroll
    for (int kk = 0; kk < 2; ++kk)
      pa[mi][kk] = *(const bf16x8*)(&Pl[w][mi * 16 + lm][kk * 32 + lq * 8]);

  // ---- V fragments (B-operand): lane reads dim (n2*16+lm) of tokens kk*32+lq*8+i ----
  bf16x8 vf[2][2];
#pragma unroll
  for (int kk = 0; kk < 2; ++kk)
#pragma unroll
    for (int n2 = 0; n2 < 2; ++n2) {
      const int nb = kk * 32 + lq * 8;           // token block; iy const, ix = 0..7
      const long tb2 = tbase + (long)(nb >> 3) * 256;
      const uint16_t* vp = QKV + co_v + n2 * 16 + lm;
      bf16x8 o;
#pragma unroll
      for (int i = 0; i < 8; ++i)
        o[i] = *(const __bf16*)(vp + (tb2 + 2 * i) * QKVN);
      vf[kk][n2] = o;
    }

  // ---- O = P V : 16 MFMAs ----
  f32x4 oacc[4][2] = {};
#pragma unroll
  for (int kk = 0; kk < 2; ++kk)
#pragma unroll
    for (int mi = 0; mi < 4; ++mi)
#pragma unroll
      for (int n2 = 0; n2 < 2; ++n2)
        oacc[mi][n2] = __builtin_amdgcn_mfma_f32_16x16x32_bf16(
            pa[mi][kk], vf[kk][n2], oacc[mi][n2], 0, 0, 0);

  // ---- normalize by row sums and scatter to token order ----
#pragma unroll
  for (int mi = 0; mi < 4; ++mi)
#pragma unroll
    for (int r = 0; r < 4; ++r) {
      const int n = mi * 16 + lq * 4 + r;
      const long t = tbase + (n >> 3) * 256 + (n & 7) * 2;
      const float rinv = 1.0f / rsum[mi][r];
#pragma unroll
      for (int n2 = 0; n2 < 2; ++n2)
        O[t * DIMC + h * HDIM + n2 * 16 + lm] = f2bf(oacc[mi][n2][r] * rinv);
    }
}

// ---------------------------------------------------------------------------
extern "C" void kernel_launch(void* const* d_in, const int* in_sizes, int n_in,
                              void* d_out, int out_size, void* d_ws, size_t ws_size,
                              hipStream_t stream)
{
  const float* x      = (const float*)d_in[0];   // [65536][512] fp32
  const float* qkv_w  = (const float*)d_in[1];   // [1536][512]  fp32
  const float* qkv_b  = (const float*)d_in[2];   // [1536]       fp32
  const float* proj_w = (const float*)d_in[3];   // [512][512]   fp32
  const float* proj_b = (const float*)d_in[4];   // [512]        fp32
  float* out = (float*)d_out;                    // [65536][512] fp32

  // workspace layout (bf16 halves)
  uint16_t* xb    = (uint16_t*)d_ws;                     // 64 MiB
  uint16_t* qwb   = xb    + (size_t)NTOK * DIMC;         // 1.5 MiB
  uint16_t* pwb   = qwb   + (size_t)QKVN * DIMC;         // 0.5 MiB
  uint16_t* qkv   = pwb   + (size_t)DIMC * DIMC;         // 192 MiB
  uint16_t* attn  = qkv   + (size_t)NTOK * QKVN;         // 64 MiB

  // 0) fp32 -> bf16 conversions
  cvt_f32_bf16<<<2048, 256, 0, stream>>>(x,      xb,  NTOK * DIMC / 4);
  cvt_f32_bf16<<<512,  256, 0, stream>>>(qkv_w,  qwb, QKVN * DIMC / 4);
  cvt_f32_bf16<<<256,  256, 0, stream>>>(proj_w, pwb, DIMC * DIMC / 4);

  // 1) QKV = x @ qkv_w^T + qkv_b   (bf16 out)
  gemm_bias_bf16<false><<<dim3(QKVN / 128, NTOK / 128), dim3(256), 0, stream>>>(
      xb, qwb, qkv_b, qkv, NTOK, QKVN, DIMC);

  // 2) windowed dilated attention with fused RoPE (1024 groups x 16 heads)
  attn_win<<<dim3(1024 * 4), dim3(256), 0, stream>>>(qkv, attn);

  // 3) out = attn @ proj_w^T + proj_b   (fp32 out)
  gemm_bias_bf16<true><<<dim3(DIMC / 128, NTOK / 128), dim3(256), 0, stream>>>(
      attn, pwb, proj_b, out, NTOK, DIMC, DIMC);
}

// Round 3
// 304.240 us; speedup vs baseline: 1.0438x; 1.0438x over previous
//
#include <hip/hip_runtime.h>
#include <hip/hip_bf16.h>
#include <stdint.h>

// ---------------- problem constants ----------------
#define DIMC  512
#define NHEAD 16
#define HDIM  32
#define NTOK  65536          // 4*128*128 tokens
#define QKVN  1536           // 3*DIMC
static constexpr float SCALE_F = 0.17677669529663687f;  // HD^-0.5

typedef __attribute__((ext_vector_type(4))) float  f32x4;
typedef __attribute__((ext_vector_type(8))) __bf16 bf16x8;

__device__ __forceinline__ uint16_t f2bf(float f) {
  union { float f; uint32_t u; } v; v.f = f;
  return (uint16_t)((v.u + 0x7FFFu + ((v.u >> 16) & 1u)) >> 16);
}

// async global->LDS, 16B/lane; LDS dest is wave-uniform base (+lane*16 by HW)
__device__ __forceinline__ void gload_lds16(const void* g, void* l) {
  __builtin_amdgcn_global_load_lds((const __attribute__((address_space(1))) void*)g,
                                   (__attribute__((address_space(3))) void*)l,
                                   16, 0, 0);
}

// ---------------------------------------------------------------------------
// fp32 -> bf16 convert (vectorized, grid-stride). n4 = element count / 4.
// ---------------------------------------------------------------------------
__global__ void cvt_f32_bf16(const float* __restrict__ src,
                             uint16_t* __restrict__ dst, int n4)
{
  int i = blockIdx.x * blockDim.x + threadIdx.x;
  const int stride = gridDim.x * blockDim.x;
  for (; i < n4; i += stride) {
    const float4 v = ((const float4*)src)[i];
    ushort4 o;
    o.x = f2bf(v.x); o.y = f2bf(v.y); o.z = f2bf(v.z); o.w = f2bf(v.w);
    ((ushort4*)dst)[i] = o;
  }
}

// ---------------------------------------------------------------------------
// 256x256 8-phase GEMM (HK-derived template): C[M,N] = A[M,K]@B[N,K]^T + bias
// 8 waves (wm=w>>2 in {0,1}, wn=w&3 in {0..3}); per-wave output 128x64 spread
// over 4 quadrants (qm,qn): rows qm*128+wm*64+[0,64), cols qn*128+wn*32+[0,32).
// LDS 128 KiB: slot s(=tile&1)*64K + {A:0,B:32K} + half*16K; half = 128x64 bf16.
// Quadrant phase reads ONLY A-half qm and B-half qn -> last-reader schedule:
//   tile T (phases 0-3): A0@{0,1} A1@{2,3} B0@{0,2} B1@{1,3}
// so re-staging region X of tile T+2 is safe from phase (last reader of T.X)+1
// (phase-p reads complete before any wave leaves phase p: compiler lgkmcnt
//  precedes the MFMAs which precede the trailing barrier).
// Stage order per iter (computing T even, T+1): p0:(T+1).A1 p1:(T+1).B1
//   p2:(T+2).A0 p3:(T+2).B0 p4:(T+2).A1 p5:(T+2).B1 p6:(T+3).A0 p7:(T+3).B0
// vmcnt(4) at END of p3 (guards T+1 for p4-p7) and END of p7 (guards T+2),
// leaving 2 half-tiles (4 loads) in flight across every barrier. Never 0.
// Swizzle (T2): logical byte o (128B rows) stored at o^((row&7)<<4);
// staged via pre-swizzled GLOBAL source (linear LDS dest), read with same XOR.
// ---------------------------------------------------------------------------
template <bool OUT_F32>
__global__ __launch_bounds__(512, 2)
void gemm256_8ph(const uint16_t* __restrict__ A,
                 const uint16_t* __restrict__ B,
                 const float* __restrict__ bias,
                 void* __restrict__ Cv,
                 int M, int N, int K, int gx)
{
  __shared__ __align__(16) char lds[131072];

  const int tid = threadIdx.x;
  const int l  = tid & 63, w = tid >> 6;
  const int wm = w >> 2,  wn = w & 3;
  const int lm = l & 15,  lq = l >> 4;

  // T1: bijective XCD swizzle (m204)
  const int nwg = gridDim.x;
  const int qq = nwg >> 3, rr = nwg & 7;
  const int xcd = blockIdx.x & 7, loc = blockIdx.x >> 3;
  const int sw = (xcd < rr ? xcd * (qq + 1) : rr * (qq + 1) + (xcd - rr) * qq) + loc;
  const long m0 = (long)(sw / gx) * 256;
  const long n0 = (long)(sw % gx) * 256;

  // staging source map: lin = ld*8192 + tid*16; row = ld*64 + (tid>>3);
  // source col-byte = ((tid&7) ^ (row&7))<<4  (inverse-swizzle, rule #21)
  const int srow  = tid >> 3;
  const int scolb = (((tid & 7) ^ (srow & 7)) << 4);
  const uint16_t* Ags = A + (m0 + srow) * (long)K + (scolb >> 1);
  const uint16_t* Bgs = B + (n0 + srow) * (long)K + (scolb >> 1);
  char* ldsW = lds + (w << 10);   // wave-uniform; + regionOff (+8192 for ld=1)

  // regionOff = slot*65536 + (B?32768:0) + half*16384 ; src rows += half*128
  auto STAGE = [&](const uint16_t* Gs, int regionOff, int half, int kt) {
    const uint16_t* s0 = Gs + (size_t)(half * 128) * K + kt;
    gload_lds16(s0,                 ldsW + regionOff);
    gload_lds16(s0 + (size_t)64 * K, ldsW + regionOff + 8192);
  };

  // fragment-read offsets (swizzled): byte = row*128 + ((kk*64+lq*16)^((lm&7)<<4))
  const int colx0 = ((lq ^ (lm & 7)) << 4);
  const int aoff0 = (wm * 64 + lm) * 128 + colx0;
  const int aoff1 = (wm * 64 + lm) * 128 + (colx0 ^ 64);
  const int boff0 = (wn * 32 + lm) * 128 + colx0;
  const int boff1 = (wn * 32 + lm) * 128 + (colx0 ^ 64);

  f32x4 acc[2][2][4][2] = {};

#define PHASE(SLOT, QM, QN, STG, VM)                                          \
  {                                                                           \
    const char* Ab = lds + (SLOT) * 65536 + (QM) * 16384;                     \
    const char* Bb = lds + (SLOT) * 65536 + 32768 + (QN) * 16384;             \
    bf16x8 af0[4], af1[4], bq0[2], bq1[2];                                    \
    _Pragma("unroll") for (int i = 0; i < 4; ++i) {                           \
      af0[i] = *(const bf16x8*)(Ab + aoff0 + i * 2048);                       \
      af1[i] = *(const bf16x8*)(Ab + aoff1 + i * 2048);                       \
    }                                                                         \
    _Pragma("unroll") for (int j = 0; j < 2; ++j) {                           \
      bq0[j] = *(const bf16x8*)(Bb + boff0 + j * 2048);                       \
      bq1[j] = *(const bf16x8*)(Bb + boff1 + j * 2048);                       \
    }                                                                         \
    STG;                                                                      \
    __builtin_amdgcn_s_barrier();                                             \
    __builtin_amdgcn_s_setprio(1);                                            \
    _Pragma("unroll") for (int i = 0; i < 4; ++i)                             \
      _Pragma("unroll") for (int j = 0; j < 2; ++j) {                         \
        acc[QM][QN][i][j] = __builtin_amdgcn_mfma_f32_16x16x32_bf16(          \
            af0[i], bq0[j], acc[QM][QN][i][j], 0, 0, 0);                      \
        acc[QM][QN][i][j] = __builtin_amdgcn_mfma_f32_16x16x32_bf16(          \
            af1[i], bq1[j], acc[QM][QN][i][j], 0, 0, 0);                      \
      }                                                                       \
    __builtin_amdgcn_s_setprio(0);                                            \
    if (VM) { asm volatile("s_waitcnt vmcnt(4)" ::: "memory"); }              \
    __builtin_amdgcn_s_barrier();                                             \
  }

  // prologue: tile0 (slot0) fully, tile1 (slot1) A0+B0  -> 12 loads/wave
  STAGE(Ags, 0,             0, 0);    // 0.A0
  STAGE(Bgs, 32768,         0, 0);    // 0.B0
  STAGE(Ags, 16384,         1, 0);    // 0.A1
  STAGE(Bgs, 49152,         1, 0);    // 0.B1
  STAGE(Ags, 65536,         0, 64);   // 1.A0
  STAGE(Bgs, 65536 + 32768, 0, 64);   // 1.B0
  asm volatile("s_waitcnt vmcnt(4)" ::: "memory");   // tile0 landed; 1.A0/B0 float
  __builtin_amdgcn_s_barrier();

  for (int t2 = 0; t2 < K / 64; t2 += 2) {
    const int k1 = (t2 + 1) * 64;
    int k2 = (t2 + 2) * 64; if (k2 >= K) k2 = 0;   // clamped: staged, never read
    int k3 = (t2 + 3) * 64; if (k3 >= K) k3 = 0;
    PHASE(0, 0, 0, STAGE(Ags, 65536 + 16384, 1, k1), 0)   // (T+1).A1
    PHASE(0, 0, 1, STAGE(Bgs, 65536 + 49152, 1, k1), 0)   // (T+1).B1
    PHASE(0, 1, 0, STAGE(Ags, 0,             0, k2), 0)   // (T+2).A0
    PHASE(0, 1, 1, STAGE(Bgs, 32768,         0, k2), 1)   // (T+2).B0 + vmcnt(4)
    PHASE(1, 0, 0, STAGE(Ags, 16384,         1, k2), 0)   // (T+2).A1
    PHASE(1, 0, 1, STAGE(Bgs, 49152,         1, k2), 0)   // (T+2).B1
    PHASE(1, 1, 0, STAGE(Ags, 65536,         0, k3), 0)   // (T+3).A0
    PHASE(1, 1, 1, STAGE(Bgs, 65536 + 32768, 0, k3), 1)   // (T+3).B0 + vmcnt(4)
  }
#undef PHASE

  // epilogue: C/D layout col = l&15, row = (l>>4)*4 + r
#pragma unroll
  for (int qm = 0; qm < 2; ++qm)
#pragma unroll
  for (int qn = 0; qn < 2; ++qn)
#pragma unroll
  for (int i = 0; i < 4; ++i)
#pragma unroll
  for (int j = 0; j < 2; ++j) {
    const long m = m0 + qm * 128 + wm * 64 + i * 16 + lq * 4;
    const long n = n0 + qn * 128 + wn * 32 + j * 16 + lm;
    const float bv = bias[n];
#pragma unroll
    for (int r = 0; r < 4; ++r) {
      const float val = acc[qm][qn][i][j][r] + bv;
      if (OUT_F32) ((float*)Cv)[(m + r) * (long)N + n] = val;
      else         ((uint16_t*)Cv)[(m + r) * (long)N + n] = f2bf(val);
    }
  }
}

// ---------------------------------------------------------------------------
// Windowed dilated attention: one wave per (group g, head h).  (unchanged)
// ---------------------------------------------------------------------------
__global__ void attn_win(const uint16_t* __restrict__ QKV,  // [NTOK][1536] bf16
                         uint16_t* __restrict__ O)          // [NTOK][512]  bf16
{
  __shared__ __align__(16) __bf16 Pl[4][64][72];

  const int tid = threadIdx.x;
  const int l  = tid & 63, w = tid >> 6;
  const int lm = l & 15,  lq = l >> 4;
  const int bid = blockIdx.x;
  const int g = bid >> 2;
  const int h = (bid & 3) * 4 + w;

  const int d1 = g & 1, d0 = (g >> 1) & 1;
  const int wx = (g >> 2) & 7, wy = (g >> 5) & 7, bb = g >> 8;
  const long tbase = ((long)(bb * 128 + wy * 16 + d0) * 128) + wx * 16 + d1;

  f32x4 invs;
#pragma unroll
  for (int i = 0; i < 4; ++i)
    invs[i] = exp2f(-1.6609640474436813f * (float)((lq & 1) * 4 + i));

  const int co_q = h * HDIM;
  const int co_k = DIMC + h * HDIM;
  const int co_v = 2 * DIMC + h * HDIM;

  bf16x8 qf[4], kf[4];
#pragma unroll
  for (int f = 0; f < 4; ++f) {
    const int n  = f * 16 + lm;
    const int iy = n >> 3, ix = n & 7;
    const float pos = (lq < 2) ? (float)iy : (float)ix;
    const long t = tbase + iy * 256 + ix * 2;
    const uint16_t* qp = QKV + t * QKVN + co_q + lq * 8;
    const uint16_t* kp = QKV + t * QKVN + co_k + lq * 8;
    {
      bf16x8 raw = *(const bf16x8*)qp, o;
#pragma unroll
      for (int i = 0; i < 4; ++i) {
        float x1 = (float)raw[2 * i], x2 = (float)raw[2 * i + 1];
        float s, c; __sincosf(pos * invs[i], &s, &c);
        o[2 * i]     = (__bf16)((x1 * c - x2 * s) * SCALE_F);
        o[2 * i + 1] = (__bf16)((x1 * s + x2 * c) * SCALE_F);
      }
      qf[f] = o;
    }
    {
      bf16x8 raw = *(const bf16x8*)kp, o;
#pragma unroll
      for (int i = 0; i < 4; ++i) {
        float x1 = (float)raw[2 * i], x2 = (float)raw[2 * i + 1];
        float s, c; __sincosf(pos * invs[i], &s, &c);
        o[2 * i]     = (__bf16)(x1 * c - x2 * s);
        o[2 * i + 1] = (__bf16)(x1 * s + x2 * c);
      }
      kf[f] = o;
    }
  }

  const f32x4 fzero = {0.f, 0.f, 0.f, 0.f};
  f32x4 s[4][4];
#pragma unroll
  for (int mi = 0; mi < 4; ++mi)
#pragma unroll
    for (int ni = 0; ni < 4; ++ni)
      s[mi][ni] = __builtin_amdgcn_mfma_f32_16x16x32_bf16(qf[mi], kf[ni], fzero, 0, 0, 0);

  float rsum[4][4];
#pragma unroll
  for (int mi = 0; mi < 4; ++mi)
#pragma unroll
    for (int r = 0; r < 4; ++r) {
      float m = s[mi][0][r];
#pragma unroll
      for (int ni = 1; ni < 4; ++ni) m = fmaxf(m, s[mi][ni][r]);
      m = fmaxf(m, __shfl_xor(m, 1));
      m = fmaxf(m, __shfl_xor(m, 2));
      m = fmaxf(m, __shfl_xor(m, 4));
      m = fmaxf(m, __shfl_xor(m, 8));
      float sum = 0.f;
#pragma unroll
      for (int ni = 0; ni < 4; ++ni) {
        float p = expf(s[mi][ni][r] - m);
        s[mi][ni][r] = p;
        sum += p;
      }
      sum += __shfl_xor(sum, 1);
      sum += __shfl_xor(sum, 2);
      sum += __shfl_xor(sum, 4);
      sum += __shfl_xor(sum, 8);
      rsum[mi][r] = sum;
    }

#pragma unroll
  for (int mi = 0; mi < 4; ++mi)
#pragma unroll
    for (int ni = 0; ni < 4; ++ni)
#pragma unroll
      for (int r = 0; r < 4; ++r)
        Pl[w][mi * 16 + lq * 4 + r][ni * 16 + lm] = (__bf16)s[mi][ni][r];

  bf16x8 pa[4][2];
#pragma unroll
  for (int mi = 0; mi < 4; ++mi)
#pragma unroll
    for (int kk = 0; kk < 2; ++kk)
      pa[mi][kk] = *(const bf16x8*)(&Pl[w][mi * 16 + lm][kk * 32 + lq * 8]);

  bf16x8 vf[2][2];
#pragma unroll
  for (int kk = 0; kk < 2; ++kk)
#pragma unroll
    for (int n2 = 0; n2 < 2; ++n2) {
      const int nb = kk * 32 + lq * 8;
      const long tb2 = tbase + (long)(nb >> 3) * 256;
      const uint16_t* vp = QKV + co_v + n2 * 16 + lm;
      bf16x8 o;
#pragma unroll
      for (int i = 0; i < 8; ++i)
        o[i] = *(const __bf16*)(vp + (tb2 + 2 * i) * QKVN);
      vf[kk][n2] = o;
    }

  f32x4 oacc[4][2] = {};
#pragma unroll
  for (int kk = 0; kk < 2; ++kk)
#pragma unroll
    for (int mi = 0; mi < 4; ++mi)
#pragma unroll
      for (int n2 = 0; n2 < 2; ++n2)
        oacc[mi][n2] = __builtin_amdgcn_mfma_f32_16x16x32_bf16(
            pa[mi][kk], vf[kk][n2], oacc[mi][n2], 0, 0, 0);

#pragma unroll
  for (int mi = 0; mi < 4; ++mi)
#pragma unroll
    for (int r = 0; r < 4; ++r) {
      const int n = mi * 16 + lq * 4 + r;
      const long t = tbase + (n >> 3) * 256 + (n & 7) * 2;
      const float rinv = 1.0f / rsum[mi][r];
#pragma unroll
      for (int n2 = 0; n2 < 2; ++n2)
        O[t * DIMC + h * HDIM + n2 * 16 + lm] = f2bf(oacc[mi][n2][r] * rinv);
    }
}

// ---------------------------------------------------------------------------
extern "C" void kernel_launch(void* const* d_in, const int* in_sizes, int n_in,
                              void* d_out, int out_size, void* d_ws, size_t ws_size,
                              hipStream_t stream)
{
  const float* x      = (const float*)d_in[0];   // [65536][512] fp32
  const float* qkv_w  = (const float*)d_in[1];   // [1536][512]  fp32
  const float* qkv_b  = (const float*)d_in[2];   // [1536]       fp32
  const float* proj_w = (const float*)d_in[3];   // [512][512]   fp32
  const float* proj_b = (const float*)d_in[4];   // [512]        fp32
  float* out = (float*)d_out;                    // [65536][512] fp32

  uint16_t* xb    = (uint16_t*)d_ws;                     // 64 MiB
  uint16_t* qwb   = xb    + (size_t)NTOK * DIMC;         // 1.5 MiB
  uint16_t* pwb   = qwb   + (size_t)QKVN * DIMC;         // 0.5 MiB
  uint16_t* qkv   = pwb   + (size_t)DIMC * DIMC;         // 192 MiB
  uint16_t* attn  = qkv   + (size_t)NTOK * QKVN;         // 64 MiB

  // 0) fp32 -> bf16 conversions
  cvt_f32_bf16<<<2048, 256, 0, stream>>>(x,      xb,  NTOK * DIMC / 4);
  cvt_f32_bf16<<<512,  256, 0, stream>>>(qkv_w,  qwb, QKVN * DIMC / 4);
  cvt_f32_bf16<<<256,  256, 0, stream>>>(proj_w, pwb, DIMC * DIMC / 4);

  // 1) QKV = x @ qkv_w^T + qkv_b   (bf16 out), 256x256 tiles: grid 256*6
  gemm256_8ph<false><<<dim3((NTOK / 256) * (QKVN / 256)), dim3(512), 0, stream>>>(
      xb, qwb, qkv_b, qkv, NTOK, QKVN, DIMC, QKVN / 256);

  // 2) windowed dilated attention with fused RoPE (1024 groups x 16 heads)
  attn_win<<<dim3(1024 * 4), dim3(256), 0, stream>>>(qkv, attn);

  // 3) out = attn @ proj_w^T + proj_b   (fp32 out), grid 256*2
  gemm256_8ph<true><<<dim3((NTOK / 256) * (DIMC / 256)), dim3(512), 0, stream>>>(
      attn, pwb, proj_b, out, NTOK, DIMC, DIMC, DIMC / 256);
}

// Round 4
// 297.875 us; speedup vs baseline: 1.0661x; 1.0214x over previous
//
#include <hip/hip_runtime.h>
#include <hip/hip_bf16.h>
#include <stdint.h>

// ---------------- problem constants ----------------
#define DIMC  512
#define NHEAD 16
#define HDIM  32
#define NTOK  65536          // 4*128*128 tokens
#define QKVN  1536           // 3*DIMC
static constexpr float SCALE_F = 0.17677669529663687f;  // HD^-0.5

typedef __attribute__((ext_vector_type(4))) float  f32x4;
typedef __attribute__((ext_vector_type(8))) __bf16 bf16x8;

__device__ __forceinline__ uint16_t f2bf(float f) {
  union { float f; uint32_t u; } v; v.f = f;
  return (uint16_t)((v.u + 0x7FFFu + ((v.u >> 16) & 1u)) >> 16);
}

// async global->LDS, 16B/lane; LDS dest is wave-uniform base (+lane*16 by HW)
__device__ __forceinline__ void gload_lds16(const void* g, void* l) {
  __builtin_amdgcn_global_load_lds((const __attribute__((address_space(1))) void*)g,
                                   (__attribute__((address_space(3))) void*)l,
                                   16, 0, 0);
}

// ---------------------------------------------------------------------------
// fp32 -> bf16 convert (vectorized, grid-stride). n4 = element count / 4.
// ---------------------------------------------------------------------------
__global__ void cvt_f32_bf16(const float* __restrict__ src,
                             uint16_t* __restrict__ dst, int n4)
{
  int i = blockIdx.x * blockDim.x + threadIdx.x;
  const int stride = gridDim.x * blockDim.x;
  for (; i < n4; i += stride) {
    const float4 v = ((const float4*)src)[i];
    ushort4 o;
    o.x = f2bf(v.x); o.y = f2bf(v.y); o.z = f2bf(v.z); o.w = f2bf(v.w);
    ((ushort4*)dst)[i] = o;
  }
}

// ---------------------------------------------------------------------------
// 256x256 8-phase GEMM with SINGLE-READ fragments.
// Wave (wm=w>>2, wn=w&3) owns, per quadrant (qm,qn):
//   rows qm*128+wm*64+[0,64), cols qn*128+wn*32+[0,32)
// af[4][2] (A rows of current qm, both kk) is read at the FIRST qn phase of
// each qm and HELD across the second; bq[qn][2][2] is read at qm=0 and HELD
// across qm=1. Per-tile LDS reads/wave: 12+4+8+0 = 24 (vs 48 in round 3).
// Read schedule per tile T (phases 0-3 of its slot):
//   A0 last read @p0, B0 @p0, B1 @p1, A1 @p2.
// Stage schedule per iter (tiles T,T+1): p0:(T+1).A1 p1:(T+1).B1 p2:(T+2).A0
//   p3:(T+2).B0+vm4 p4:(T+2).A1 p5:(T+2).B1 p6:(T+3).A0 p7:(T+3).B0+vm4
// Safety: every region's re-stage is >=2 phases after its last read; p3's
// vmcnt(4) completes (T+1).A1/B1 (+ all older, FIFO) before p4 reads slot1;
// p7's vmcnt(4) completes (T+2).A0/B0 before next-iter p0.
// Swizzle (T2): logical byte o stored at o^((row&7)<<4); staged via
// pre-swizzled GLOBAL source (linear LDS dest), read with the same XOR.
// ---------------------------------------------------------------------------
template <bool OUT_F32>
__global__ __launch_bounds__(512, 2)
void gemm256_8ph(const uint16_t* __restrict__ A,
                 const uint16_t* __restrict__ B,
                 const float* __restrict__ bias,
                 void* __restrict__ Cv,
                 int M, int N, int K, int gx)
{
  __shared__ __align__(16) char lds[131072];

  const int tid = threadIdx.x;
  const int l  = tid & 63, w = tid >> 6;
  const int wm = w >> 2,  wn = w & 3;
  const int lm = l & 15,  lq = l >> 4;

  // T1: bijective XCD swizzle (m204)
  const int nwg = gridDim.x;
  const int qq = nwg >> 3, rr = nwg & 7;
  const int xcd = blockIdx.x & 7, loc = blockIdx.x >> 3;
  const int sw = (xcd < rr ? xcd * (qq + 1) : rr * (qq + 1) + (xcd - rr) * qq) + loc;
  const long m0 = (long)(sw / gx) * 256;
  const long n0 = (long)(sw % gx) * 256;

  // staging source map: row = ld*64 + (tid>>3); col-byte = ((tid&7)^(row&7))<<4
  const int srow  = tid >> 3;
  const int scolb = (((tid & 7) ^ (srow & 7)) << 4);
  const uint16_t* Ags = A + (m0 + srow) * (long)K + (scolb >> 1);
  const uint16_t* Bgs = B + (n0 + srow) * (long)K + (scolb >> 1);
  char* ldsW = lds + (w << 10);

  auto STAGE = [&](const uint16_t* Gs, int regionOff, int half, int kt) {
    const uint16_t* s0 = Gs + (size_t)(half * 128) * K + kt;
    gload_lds16(s0,                  ldsW + regionOff);
    gload_lds16(s0 + (size_t)64 * K, ldsW + regionOff + 8192);
  };

  // fragment-read offsets (swizzled)
  const int colx0 = ((lq ^ (lm & 7)) << 4);
  const int aoff0 = (wm * 64 + lm) * 128 + colx0;
  const int aoff1 = (wm * 64 + lm) * 128 + (colx0 ^ 64);
  const int boff0 = (wn * 32 + lm) * 128 + colx0;
  const int boff1 = (wn * 32 + lm) * 128 + (colx0 ^ 64);

  f32x4  acc[2][2][4][2] = {};
  bf16x8 af[4][2];        // A frags of current qm (held across qn phases)
  bf16x8 bq[2][2][2];     // [qn][nj][kk] (held across qm phases)

  // RDA/RDB are compile-time 0/1 flags
#define PHASE(SLOT, QM, QN, RDA, RDB, STG, VM)                                \
  {                                                                           \
    if (RDA) {                                                                \
      const char* Ab = lds + (SLOT) * 65536 + (QM) * 16384;                   \
      _Pragma("unroll") for (int i = 0; i < 4; ++i) {                         \
        af[i][0] = *(const bf16x8*)(Ab + aoff0 + i * 2048);                   \
        af[i][1] = *(const bf16x8*)(Ab + aoff1 + i * 2048);                   \
      }                                                                       \
    }                                                                         \
    if (RDB) {                                                                \
      const char* Bb = lds + (SLOT) * 65536 + 32768 + (QN) * 16384;           \
      _Pragma("unroll") for (int j = 0; j < 2; ++j) {                         \
        bq[QN][j][0] = *(const bf16x8*)(Bb + boff0 + j * 2048);               \
        bq[QN][j][1] = *(const bf16x8*)(Bb + boff1 + j * 2048);               \
      }                                                                       \
    }                                                                         \
    STG;                                                                      \
    __builtin_amdgcn_s_barrier();                                             \
    __builtin_amdgcn_s_setprio(1);                                            \
    _Pragma("unroll") for (int kk = 0; kk < 2; ++kk)                          \
      _Pragma("unroll") for (int i = 0; i < 4; ++i)                           \
        _Pragma("unroll") for (int j = 0; j < 2; ++j)                         \
          acc[QM][QN][i][j] = __builtin_amdgcn_mfma_f32_16x16x32_bf16(        \
              af[i][kk], bq[QN][j][kk], acc[QM][QN][i][j], 0, 0, 0);          \
    __builtin_amdgcn_s_setprio(0);                                            \
    if (VM) { asm volatile("s_waitcnt vmcnt(4)" ::: "memory"); }              \
    __builtin_amdgcn_s_barrier();                                             \
  }

  // prologue: tile0 fully, tile1 A0+B0
  STAGE(Ags, 0,             0, 0);    // 0.A0
  STAGE(Bgs, 32768,         0, 0);    // 0.B0
  STAGE(Ags, 16384,         1, 0);    // 0.A1
  STAGE(Bgs, 49152,         1, 0);    // 0.B1
  STAGE(Ags, 65536,         0, 64);   // 1.A0
  STAGE(Bgs, 65536 + 32768, 0, 64);   // 1.B0
  asm volatile("s_waitcnt vmcnt(4)" ::: "memory");   // tile0 landed
  __builtin_amdgcn_s_barrier();

  for (int t2 = 0; t2 < K / 64; t2 += 2) {
    const int k1 = (t2 + 1) * 64;
    int k2 = (t2 + 2) * 64; if (k2 >= K) k2 = 0;   // clamped: staged, never read
    int k3 = (t2 + 3) * 64; if (k3 >= K) k3 = 0;
    PHASE(0, 0, 0, 1, 1, STAGE(Ags, 65536 + 16384, 1, k1), 0)   // (T+1).A1
    PHASE(0, 0, 1, 0, 1, STAGE(Bgs, 65536 + 49152, 1, k1), 0)   // (T+1).B1
    PHASE(0, 1, 0, 1, 0, STAGE(Ags, 0,             0, k2), 0)   // (T+2).A0
    PHASE(0, 1, 1, 0, 0, STAGE(Bgs, 32768,         0, k2), 1)   // (T+2).B0 +vm4
    PHASE(1, 0, 0, 1, 1, STAGE(Ags, 16384,         1, k2), 0)   // (T+2).A1
    PHASE(1, 0, 1, 0, 1, STAGE(Bgs, 49152,         1, k2), 0)   // (T+2).B1
    PHASE(1, 1, 0, 1, 0, STAGE(Ags, 65536,         0, k3), 0)   // (T+3).A0
    PHASE(1, 1, 1, 0, 0, STAGE(Bgs, 65536 + 32768, 0, k3), 1)   // (T+3).B0 +vm4
  }
#undef PHASE

  // epilogue: C/D layout col = l&15, row = (l>>4)*4 + r
#pragma unroll
  for (int qm = 0; qm < 2; ++qm)
#pragma unroll
  for (int qn = 0; qn < 2; ++qn)
#pragma unroll
  for (int i = 0; i < 4; ++i)
#pragma unroll
  for (int j = 0; j < 2; ++j) {
    const long m = m0 + qm * 128 + wm * 64 + i * 16 + lq * 4;
    const long n = n0 + qn * 128 + wn * 32 + j * 16 + lm;
    const float bv = bias[n];
#pragma unroll
    for (int r = 0; r < 4; ++r) {
      const float val = acc[qm][qn][i][j][r] + bv;
      if (OUT_F32) ((float*)Cv)[(m + r) * (long)N + n] = val;
      else         ((uint16_t*)Cv)[(m + r) * (long)N + n] = f2bf(val);
    }
  }
}

// ---------------------------------------------------------------------------
// Windowed dilated attention: one wave per (group g, head h).  (unchanged)
// ---------------------------------------------------------------------------
__global__ void attn_win(const uint16_t* __restrict__ QKV,  // [NTOK][1536] bf16
                         uint16_t* __restrict__ O)          // [NTOK][512]  bf16
{
  __shared__ __align__(16) __bf16 Pl[4][64][72];

  const int tid = threadIdx.x;
  const int l  = tid & 63, w = tid >> 6;
  const int lm = l & 15,  lq = l >> 4;
  const int bid = blockIdx.x;
  const int g = bid >> 2;
  const int h = (bid & 3) * 4 + w;

  const int d1 = g & 1, d0 = (g >> 1) & 1;
  const int wx = (g >> 2) & 7, wy = (g >> 5) & 7, bb = g >> 8;
  const long tbase = ((long)(bb * 128 + wy * 16 + d0) * 128) + wx * 16 + d1;

  f32x4 invs;
#pragma unroll
  for (int i = 0; i < 4; ++i)
    invs[i] = exp2f(-1.6609640474436813f * (float)((lq & 1) * 4 + i));

  const int co_q = h * HDIM;
  const int co_k = DIMC + h * HDIM;
  const int co_v = 2 * DIMC + h * HDIM;

  bf16x8 qf[4], kf[4];
#pragma unroll
  for (int f = 0; f < 4; ++f) {
    const int n  = f * 16 + lm;
    const int iy = n >> 3, ix = n & 7;
    const float pos = (lq < 2) ? (float)iy : (float)ix;
    const long t = tbase + iy * 256 + ix * 2;
    const uint16_t* qp = QKV + t * QKVN + co_q + lq * 8;
    const uint16_t* kp = QKV + t * QKVN + co_k + lq * 8;
    {
      bf16x8 raw = *(const bf16x8*)qp, o;
#pragma unroll
      for (int i = 0; i < 4; ++i) {
        float x1 = (float)raw[2 * i], x2 = (float)raw[2 * i + 1];
        float s, c; __sincosf(pos * invs[i], &s, &c);
        o[2 * i]     = (__bf16)((x1 * c - x2 * s) * SCALE_F);
        o[2 * i + 1] = (__bf16)((x1 * s + x2 * c) * SCALE_F);
      }
      qf[f] = o;
    }
    {
      bf16x8 raw = *(const bf16x8*)kp, o;
#pragma unroll
      for (int i = 0; i < 4; ++i) {
        float x1 = (float)raw[2 * i], x2 = (float)raw[2 * i + 1];
        float s, c; __sincosf(pos * invs[i], &s, &c);
        o[2 * i]     = (__bf16)(x1 * c - x2 * s);
        o[2 * i + 1] = (__bf16)(x1 * s + x2 * c);
      }
      kf[f] = o;
    }
  }

  const f32x4 fzero = {0.f, 0.f, 0.f, 0.f};
  f32x4 s[4][4];
#pragma unroll
  for (int mi = 0; mi < 4; ++mi)
#pragma unroll
    for (int ni = 0; ni < 4; ++ni)
      s[mi][ni] = __builtin_amdgcn_mfma_f32_16x16x32_bf16(qf[mi], kf[ni], fzero, 0, 0, 0);

  float rsum[4][4];
#pragma unroll
  for (int mi = 0; mi < 4; ++mi)
#pragma unroll
    for (int r = 0; r < 4; ++r) {
      float m = s[mi][0][r];
#pragma unroll
      for (int ni = 1; ni < 4; ++ni) m = fmaxf(m, s[mi][ni][r]);
      m = fmaxf(m, __shfl_xor(m, 1));
      m = fmaxf(m, __shfl_xor(m, 2));
      m = fmaxf(m, __shfl_xor(m, 4));
      m = fmaxf(m, __shfl_xor(m, 8));
      float sum = 0.f;
#pragma unroll
      for (int ni = 0; ni < 4; ++ni) {
        float p = expf(s[mi][ni][r] - m);
        s[mi][ni][r] = p;
        sum += p;
      }
      sum += __shfl_xor(sum, 1);
      sum += __shfl_xor(sum, 2);
      sum += __shfl_xor(sum, 4);
      sum += __shfl_xor(sum, 8);
      rsum[mi][r] = sum;
    }

#pragma unroll
  for (int mi = 0; mi < 4; ++mi)
#pragma unroll
    for (int ni = 0; ni < 4; ++ni)
#pragma unroll
      for (int r = 0; r < 4; ++r)
        Pl[w][mi * 16 + lq * 4 + r][ni * 16 + lm] = (__bf16)s[mi][ni][r];

  bf16x8 pa[4][2];
#pragma unroll
  for (int mi = 0; mi < 4; ++mi)
#pragma unroll
    for (int kk = 0; kk < 2; ++kk)
      pa[mi][kk] = *(const bf16x8*)(&Pl[w][mi * 16 + lm][kk * 32 + lq * 8]);

  bf16x8 vf[2][2];
#pragma unroll
  for (int kk = 0; kk < 2; ++kk)
#pragma unroll
    for (int n2 = 0; n2 < 2; ++n2) {
      const int nb = kk * 32 + lq * 8;
      const long tb2 = tbase + (long)(nb >> 3) * 256;
      const uint16_t* vp = QKV + co_v + n2 * 16 + lm;
      bf16x8 o;
#pragma unroll
      for (int i = 0; i < 8; ++i)
        o[i] = *(const __bf16*)(vp + (tb2 + 2 * i) * QKVN);
      vf[kk][n2] = o;
    }

  f32x4 oacc[4][2] = {};
#pragma unroll
  for (int kk = 0; kk < 2; ++kk)
#pragma unroll
    for (int mi = 0; mi < 4; ++mi)
#pragma unroll
      for (int n2 = 0; n2 < 2; ++n2)
        oacc[mi][n2] = __builtin_amdgcn_mfma_f32_16x16x32_bf16(
            pa[mi][kk], vf[kk][n2], oacc[mi][n2], 0, 0, 0);

#pragma unroll
  for (int mi = 0; mi < 4; ++mi)
#pragma unroll
    for (int r = 0; r < 4; ++r) {
      const int n = mi * 16 + lq * 4 + r;
      const long t = tbase + (n >> 3) * 256 + (n & 7) * 2;
      const float rinv = 1.0f / rsum[mi][r];
#pragma unroll
      for (int n2 = 0; n2 < 2; ++n2)
        O[t * DIMC + h * HDIM + n2 * 16 + lm] = f2bf(oacc[mi][n2][r] * rinv);
    }
}

// ---------------------------------------------------------------------------
extern "C" void kernel_launch(void* const* d_in, const int* in_sizes, int n_in,
                              void* d_out, int out_size, void* d_ws, size_t ws_size,
                              hipStream_t stream)
{
  const float* x      = (const float*)d_in[0];   // [65536][512] fp32
  const float* qkv_w  = (const float*)d_in[1];   // [1536][512]  fp32
  const float* qkv_b  = (const float*)d_in[2];   // [1536]       fp32
  const float* proj_w = (const float*)d_in[3];   // [512][512]   fp32
  const float* proj_b = (const float*)d_in[4];   // [512]        fp32
  float* out = (float*)d_out;                    // [65536][512] fp32

  uint16_t* xb    = (uint16_t*)d_ws;                     // 64 MiB
  uint16_t* qwb   = xb    + (size_t)NTOK * DIMC;         // 1.5 MiB
  uint16_t* pwb   = qwb   + (size_t)QKVN * DIMC;         // 0.5 MiB
  uint16_t* qkv   = pwb   + (size_t)DIMC * DIMC;         // 192 MiB
  uint16_t* attn  = qkv   + (size_t)NTOK * QKVN;         // 64 MiB

  // 0) fp32 -> bf16 conversions
  cvt_f32_bf16<<<2048, 256, 0, stream>>>(x,      xb,  NTOK * DIMC / 4);
  cvt_f32_bf16<<<512,  256, 0, stream>>>(qkv_w,  qwb, QKVN * DIMC / 4);
  cvt_f32_bf16<<<256,  256, 0, stream>>>(proj_w, pwb, DIMC * DIMC / 4);

  // 1) QKV = x @ qkv_w^T + qkv_b   (bf16 out)
  gemm256_8ph<false><<<dim3((NTOK / 256) * (QKVN / 256)), dim3(512), 0, stream>>>(
      xb, qwb, qkv_b, qkv, NTOK, QKVN, DIMC, QKVN / 256);

  // 2) windowed dilated attention with fused RoPE (1024 groups x 16 heads)
  attn_win<<<dim3(1024 * 4), dim3(256), 0, stream>>>(qkv, attn);

  // 3) out = attn @ proj_w^T + proj_b   (fp32 out)
  gemm256_8ph<true><<<dim3((NTOK / 256) * (DIMC / 256)), dim3(512), 0, stream>>>(
      attn, pwb, proj_b, out, NTOK, DIMC, DIMC, DIMC / 256);
}